// Round 7
// baseline (202.597 us; speedup 1.0000x reference)
//
#include <hip/hip_runtime.h>
#include <hip/hip_bf16.h>

// B=16, N=1024, M=8192.
//   d[b,n,m] = || binder[b,n,:] - target[m,:] ||
//   attract[b] = mean of 204 smallest (min_m d) over n;  repel[b] = sum relu(3-d)^2
//   out[b] = 10*attract + 5*repel
//
// R7 (R6 post-mortem: 3 rounds of inner-loop micro-opt all neutral at ~40us ->
// the cost is per-pair WORK (~70cyc/iter incl. 47%-taken clash branch), not the
// pipe. So cut the work):
//  - binder_min_kernel: full 134M-pair scan but MIN-ONLY: 17 slots/iter
//    (ds_read_b128 + 12 fma + 4 min), no cmp/branch/exec churn.
//  - repel via uniform grid: targets binned into 20^3 cells (6 Angstrom);
//    each point scans a fixed 2x2x2 neighborhood that exactly covers its
//    radius-3 ball (cell=6=ball diameter; consistent clamping -> exact).
//    ~25x less repel work, uniform control flow.
//  - reduce: proven bit-bisection top-k (exact), + 64 repel partials.

#define BB 16
#define NN 1024
#define MM 8192
#define MT 64           // targets per chunk (min kernel)
#define MC (MM / MT)    // 128 m-chunks
#define KSEL 204        // int(0.2 * 1024)

#define NG   20         // grid cells per dim
#define CS   6.0f       // cell size
#define GLO  60.0f      // grid origin offset: cell = floor((x+GLO)/CS)
#define NCELL (NG * NG * NG)
#define CAP  256        // bucket capacity (peak cell expectation ~112, +13 sigma)

// ---- target binning (8192 threads) ----
__global__ __launch_bounds__(256) void binder_bin_kernel(
    const float* __restrict__ target,   // [M, 3]
    int* __restrict__ cnt,              // [NCELL], pre-zeroed
    float4* __restrict__ bucket)        // [NCELL, CAP]
{
    const int i = blockIdx.x * 256 + threadIdx.x;
    const float tx = target[3 * i + 0];
    const float ty = target[3 * i + 1];
    const float tz = target[3 * i + 2];
    int cx = (int)floorf((tx + GLO) * (1.0f / CS));
    int cy = (int)floorf((ty + GLO) * (1.0f / CS));
    int cz = (int)floorf((tz + GLO) * (1.0f / CS));
    cx = min(max(cx, 0), NG - 1);
    cy = min(max(cy, 0), NG - 1);
    cz = min(max(cz, 0), NG - 1);
    const int cell = (cz * NG + cy) * NG + cx;
    const int idx = atomicAdd(&cnt[cell], 1);
    if (idx < CAP) bucket[(size_t)cell * CAP + idx] = make_float4(tx, ty, tz, 0.0f);
}

// ---- min-only full scan: 17 VALU slots / iter ----
__global__ __launch_bounds__(256, 8) void binder_min_kernel(
    const float* __restrict__ binder,   // [B, N, 3]
    const float* __restrict__ target,   // [M, 3]
    float* __restrict__ min_part)       // [B, MC, N] min d^2 per chunk
{
    __shared__ float4 s4[MT];           // (-2tx, -2ty, -2tz, |t|^2)

    const int mc  = blockIdx.x;
    const int b   = blockIdx.y;
    const int tid = threadIdx.x;

    if (tid < MT) {
        const float* tp = target + (mc * MT + tid) * 3;
        const float tx = tp[0], ty = tp[1], tz = tp[2];
        s4[tid] = make_float4(-2.0f * tx, -2.0f * ty, -2.0f * tz,
                              fmaf(tx, tx, fmaf(ty, ty, tz * tz)));
    }
    __syncthreads();

    // 4 binder points per thread; 48B contiguous/lane, 16B-aligned.
    const float* bp = binder + ((size_t)b * NN + tid * 4) * 3;
    const float4 f0 = ((const float4*)bp)[0];
    const float4 f1 = ((const float4*)bp)[1];
    const float4 f2 = ((const float4*)bp)[2];
    const float x0 = f0.x, y0 = f0.y, z0 = f0.z;
    const float x1 = f0.w, y1 = f1.x, z1 = f1.y;
    const float x2 = f1.z, y2 = f1.w, z2 = f2.x;
    const float x3 = f2.y, y3 = f2.z, z3 = f2.w;
    const float q0 = fmaf(x0, x0, fmaf(y0, y0, z0 * z0));
    const float q1 = fmaf(x1, x1, fmaf(y1, y1, z1 * z1));
    const float q2 = fmaf(x2, x2, fmaf(y2, y2, z2 * z2));
    const float q3 = fmaf(x3, x3, fmaf(y3, y3, z3 * z3));

    float m0 = 3.4e38f, m1 = 3.4e38f, m2 = 3.4e38f, m3 = 3.4e38f;

#pragma unroll 4
    for (int m = 0; m < MT; ++m) {
        const float4 s = s4[m];   // wave-uniform addr -> broadcast b128
        // f = |t|^2 - 2 t.x   (d^2 = f + q, re-attached after the loop)
        const float fa = fmaf(s.x, x0, fmaf(s.y, y0, fmaf(s.z, z0, s.w)));
        const float fb = fmaf(s.x, x1, fmaf(s.y, y1, fmaf(s.z, z1, s.w)));
        const float fc = fmaf(s.x, x2, fmaf(s.y, y2, fmaf(s.z, z2, s.w)));
        const float fd = fmaf(s.x, x3, fmaf(s.y, y3, fmaf(s.z, z3, s.w)));
        m0 = fminf(m0, fa);
        m1 = fminf(m1, fb);
        m2 = fminf(m2, fc);
        m3 = fminf(m3, fd);
    }

    // re-attach q, clamp cancellation negatives; coalesced dwordx4 store
    const float4 mout = make_float4(fmaxf(m0 + q0, 0.0f), fmaxf(m1 + q1, 0.0f),
                                    fmaxf(m2 + q2, 0.0f), fmaxf(m3 + q3, 0.0f));
    ((float4*)min_part)[(size_t)(b * MC + mc) * (NN / 4) + tid] = mout;
}

// ---- repel via grid: fixed 2x2x2 neighborhood, exact cover of ball(p,3) ----
__global__ __launch_bounds__(256) void binder_repel_kernel(
    const float* __restrict__ binder,   // [B, N, 3]
    const int* __restrict__ cnt,        // [NCELL]
    const float4* __restrict__ bucket,  // [NCELL, CAP]
    float* __restrict__ repel_part)     // [B, 4]
{
    __shared__ float wred[4];

    const int nc  = blockIdx.x;         // 4 point-chunks of 256
    const int b   = blockIdx.y;
    const int tid = threadIdx.x;
    const int n   = nc * 256 + tid;

    const float* bp = binder + ((size_t)b * NN + n) * 3;
    const float px = bp[0], py = bp[1], pz = bp[2];

    // base cell of the ball's low corner; {i,i+1} covers [p-3, p+3] per dim
    int ix = (int)floorf((px - 3.0f + GLO) * (1.0f / CS));
    int iy = (int)floorf((py - 3.0f + GLO) * (1.0f / CS));
    int iz = (int)floorf((pz - 3.0f + GLO) * (1.0f / CS));
    ix = min(max(ix, 0), NG - 2);
    iy = min(max(iy, 0), NG - 2);
    iz = min(max(iz, 0), NG - 2);

    float r = 0.0f;
#pragma unroll
    for (int s = 0; s < 8; ++s) {
        const int cell = ((iz + (s >> 2)) * NG + (iy + ((s >> 1) & 1))) * NG
                       + (ix + (s & 1));
        const int c = min(cnt[cell], CAP);
        const float4* bk = bucket + (size_t)cell * CAP;
        for (int j = 0; j < c; ++j) {
            const float4 t = bk[j];
            const float dx = px - t.x, dy = py - t.y, dz = pz - t.z;
            const float d2 = fmaf(dx, dx, fmaf(dy, dy, dz * dz));
            if (d2 < 9.0f) {
                const float cc = 3.0f - __builtin_amdgcn_sqrtf(d2);
                r = fmaf(cc, cc, r);
            }
        }
    }

#pragma unroll
    for (int off = 32; off > 0; off >>= 1) r += __shfl_down(r, off);
    if ((tid & 63) == 0) wred[tid >> 6] = r;
    __syncthreads();
    if (tid == 0) repel_part[b * 4 + nc] = wred[0] + wred[1] + wred[2] + wred[3];
}

// ---- final reduce: fold chunk mins, exact k-smallest via bit-bisection ----
__global__ __launch_bounds__(256) void binder_reduce_kernel(
    const float* __restrict__ min_part,    // [B, MC, N]
    const float* __restrict__ repel_part,  // [B, 4]
    float* __restrict__ out)               // [B]
{
    __shared__ unsigned us[NN];
    __shared__ float wsum[4];
    __shared__ int   wcnt[4];
    __shared__ float rsum;

    const int b    = blockIdx.x;
    const int tid  = threadIdx.x;
    const int lane = tid & 63;
    const int wid  = tid >> 6;

    const float4* mp = (const float4*)min_part + (size_t)b * MC * (NN / 4) + tid;
    float4 a = mp[0];
    for (int c = 1; c < MC; ++c) {
        const float4 q = mp[(size_t)c * (NN / 4)];
        a.x = fminf(a.x, q.x); a.y = fminf(a.y, q.y);
        a.z = fminf(a.z, q.z); a.w = fminf(a.w, q.w);
    }
    unsigned u[4] = {__float_as_uint(a.x), __float_as_uint(a.y),
                     __float_as_uint(a.z), __float_as_uint(a.w)};
    us[tid * 4 + 0] = u[0];
    us[tid * 4 + 1] = u[1];
    us[tid * 4 + 2] = u[2];
    us[tid * 4 + 3] = u[3];
    __syncthreads();

    unsigned ub[16];
#pragma unroll
    for (int i = 0; i < 16; ++i) ub[i] = us[lane + 64 * i];

    // bisection: invariant count(x < lo) < KSEL; final lo = KSEL-th smallest.
    unsigned lo = 0u;
    for (int bit = 30; bit >= 0; --bit) {
        const unsigned mid = lo | (1u << bit);
        int c = 0;
#pragma unroll
        for (int i = 0; i < 16; ++i) c += (ub[i] < mid) ? 1 : 0;
#pragma unroll
        for (int off = 32; off > 0; off >>= 1) c += __shfl_down(c, off);
        c = __shfl(c, 0);
        if (c < KSEL) lo = mid;
    }

    float sum = 0.0f;
    int   cl  = 0;
#pragma unroll
    for (int i = 0; i < 4; ++i) {
        if (u[i] < lo) {
            sum += __builtin_amdgcn_sqrtf(__uint_as_float(u[i]));
            ++cl;
        }
    }
#pragma unroll
    for (int off = 32; off > 0; off >>= 1) {
        sum += __shfl_down(sum, off);
        cl  += __shfl_down(cl, off);
    }
    if (lane == 0) { wsum[wid] = sum; wcnt[wid] = cl; }

    if (wid == 0) {
        float r = (lane < 4) ? repel_part[b * 4 + lane] : 0.0f;
#pragma unroll
        for (int off = 32; off > 0; off >>= 1) r += __shfl_down(r, off);
        if (lane == 0) rsum = r;
    }
    __syncthreads();

    if (tid == 0) {
        const float total = wsum[0] + wsum[1] + wsum[2] + wsum[3];
        const int   cnt2  = wcnt[0] + wcnt[1] + wcnt[2] + wcnt[3];
        const float att   = total + (float)(KSEL - cnt2)
                                    * __builtin_amdgcn_sqrtf(__uint_as_float(lo));
        out[b] = 10.0f * (att / (float)KSEL) + 5.0f * rsum;
    }
}

extern "C" void kernel_launch(void* const* d_in, const int* in_sizes, int n_in,
                              void* d_out, int out_size, void* d_ws, size_t ws_size,
                              hipStream_t stream) {
    const float* binder = (const float*)d_in[0];   // [16,1024,3] fp32
    const float* target = (const float*)d_in[1];   // [8192,3]   fp32
    float* out = (float*)d_out;                    // [16]       fp32

    // ws layout (1 KiB-aligned): min_part 8 MiB | repel_part 1 KiB |
    //                            cnt 32 KiB | buckets 32 MiB
    char* w = (char*)d_ws;
    float*  min_part   = (float*)w;                                  // 8 MiB
    float*  repel_part = (float*)(w + (8u << 20));                   // 64 floats
    int*    cnt        = (int*)(w + (8u << 20) + 1024);              // NCELL ints
    float4* bucket     = (float4*)(w + (8u << 20) + 1024 + (32u << 10));

    hipMemsetAsync(cnt, 0, NCELL * sizeof(int), stream);

    binder_bin_kernel<<<MM / 256, 256, 0, stream>>>(target, cnt, bucket);
    dim3 g1(MC, BB);   // 128 x 16 = 2048 blocks
    binder_min_kernel<<<g1, 256, 0, stream>>>(binder, target, min_part);
    dim3 g2(4, BB);    // 4 x 16 = 64 blocks
    binder_repel_kernel<<<g2, 256, 0, stream>>>(binder, cnt, bucket, repel_part);
    binder_reduce_kernel<<<BB, 256, 0, stream>>>(min_part, repel_part, out);
}

// Round 8
// 110.343 us; speedup vs baseline: 1.8361x; 1.8361x over previous
//
#include <hip/hip_runtime.h>
#include <hip/hip_bf16.h>

// B=16, N=1024, M=8192.
//   d[b,n,m] = || binder[b,n,:] - target[m,:] ||
//   attract[b] = mean of 204 smallest (min_m d) over n;  repel[b] = sum relu(3-d)^2
//   out[b] = 10*attract + 5*repel
//
// R8 (R7 post-mortem: min-only scan worked (~25us); grid repel was 107us from
// 64 blocks x serial divergent gathers):
//  - repel: WAVE-PER-POINT. 16384 waves (4096 blocks); lanes stride within a
//    cell bucket -> coalesced float4 loads, ~16 loads/lane, shuffle-reduce,
//    per-point store. Latency hidden by 16 blocks/CU.
//  - min: 8 points/thread (2 batches per block, 1024 blocks, 4/CU) -> halves
//    ds_read_b128 per pair; ~4.1 VALU slots/pair.

#define BB 16
#define NN 1024
#define MM 8192
#define MT 64           // targets per chunk (min kernel)
#define MC (MM / MT)    // 128 m-chunks
#define KSEL 204        // int(0.2 * 1024)

#define NG   20         // grid cells per dim
#define CS   6.0f       // cell size
#define GLO  60.0f      // grid origin offset: cell = floor((x+GLO)/CS)
#define NCELL (NG * NG * NG)
#define CAP  256        // bucket capacity (peak cell expectation ~110, +13 sigma)

// ---- target binning ----
__global__ __launch_bounds__(256) void binder_bin_kernel(
    const float* __restrict__ target,   // [M, 3]
    int* __restrict__ cnt,              // [NCELL], pre-zeroed
    float4* __restrict__ bucket)        // [NCELL, CAP]
{
    const int i = blockIdx.x * 256 + threadIdx.x;
    const float tx = target[3 * i + 0];
    const float ty = target[3 * i + 1];
    const float tz = target[3 * i + 2];
    int cx = (int)floorf((tx + GLO) * (1.0f / CS));
    int cy = (int)floorf((ty + GLO) * (1.0f / CS));
    int cz = (int)floorf((tz + GLO) * (1.0f / CS));
    cx = min(max(cx, 0), NG - 1);
    cy = min(max(cy, 0), NG - 1);
    cz = min(max(cz, 0), NG - 1);
    const int cell = (cz * NG + cy) * NG + cx;
    const int idx = atomicAdd(&cnt[cell], 1);
    if (idx < CAP) bucket[(size_t)cell * CAP + idx] = make_float4(tx, ty, tz, 0.0f);
}

// ---- min-only full scan: 8 points/thread, 2 batches/block ----
__global__ __launch_bounds__(256) void binder_min_kernel(
    const float* __restrict__ binder,   // [B, N, 3]
    const float* __restrict__ target,   // [M, 3]
    float* __restrict__ min_part)       // [B, MC, N] min d^2 per chunk
{
    __shared__ float4 s4[MT];           // (-2tx, -2ty, -2tz, |t|^2)

    const int mc  = blockIdx.x;
    const int tid = threadIdx.x;

    if (tid < MT) {
        const float* tp = target + (mc * MT + tid) * 3;
        const float tx = tp[0], ty = tp[1], tz = tp[2];
        s4[tid] = make_float4(-2.0f * tx, -2.0f * ty, -2.0f * tz,
                              fmaf(tx, tx, fmaf(ty, ty, tz * tz)));
    }
    __syncthreads();

    const int b = blockIdx.y * 2 + (tid >> 7);   // 2 batches per block
    const int t = tid & 127;                     // points n = 8t .. 8t+7

    // 8 binder points: 96B contiguous per thread, 6x dwordx4
    const float* bp = binder + ((size_t)b * NN + t * 8) * 3;
    const float4 g0 = ((const float4*)bp)[0];
    const float4 g1 = ((const float4*)bp)[1];
    const float4 g2 = ((const float4*)bp)[2];
    const float4 g3 = ((const float4*)bp)[3];
    const float4 g4 = ((const float4*)bp)[4];
    const float4 g5 = ((const float4*)bp)[5];
    const float x[8] = {g0.x, g0.w, g1.z, g2.y, g3.x, g3.w, g4.z, g5.y};
    const float y[8] = {g0.y, g1.x, g1.w, g2.z, g3.y, g4.x, g4.w, g5.z};
    const float z[8] = {g0.z, g1.y, g2.x, g2.w, g3.z, g4.y, g5.x, g5.w};

    float q[8], mn[8];
#pragma unroll
    for (int p = 0; p < 8; ++p) {
        q[p]  = fmaf(x[p], x[p], fmaf(y[p], y[p], z[p] * z[p]));
        mn[p] = 3.4e38f;
    }

#pragma unroll 4
    for (int m = 0; m < MT; ++m) {
        const float4 s = s4[m];   // wave-uniform -> broadcast ds_read_b128
#pragma unroll
        for (int p = 0; p < 8; ++p) {
            // f = |t|^2 - 2 t.x   (d^2 = f + q, re-attached after loop)
            const float f = fmaf(s.x, x[p], fmaf(s.y, y[p], fmaf(s.z, z[p], s.w)));
            mn[p] = fminf(mn[p], f);
        }
    }

    float4* outp = (float4*)min_part + (size_t)(b * MC + mc) * (NN / 4) + t * 2;
    outp[0] = make_float4(fmaxf(mn[0] + q[0], 0.0f), fmaxf(mn[1] + q[1], 0.0f),
                          fmaxf(mn[2] + q[2], 0.0f), fmaxf(mn[3] + q[3], 0.0f));
    outp[1] = make_float4(fmaxf(mn[4] + q[4], 0.0f), fmaxf(mn[5] + q[5], 0.0f),
                          fmaxf(mn[6] + q[6], 0.0f), fmaxf(mn[7] + q[7], 0.0f));
}

// ---- repel: one wave per point; lanes stride within cell buckets ----
__global__ __launch_bounds__(256) void binder_repel_kernel(
    const float* __restrict__ binder,   // [B, N, 3]
    const int* __restrict__ cnt,        // [NCELL]
    const float4* __restrict__ bucket,  // [NCELL, CAP]
    float* __restrict__ repel_pt)       // [B * N] per-point repel sum
{
    const int lane = threadIdx.x & 63;
    const int pi   = blockIdx.x * 4 + (threadIdx.x >> 6);   // 0..16383
    const int b    = pi >> 10;
    const int n    = pi & (NN - 1);

    const float* bp = binder + ((size_t)b * NN + n) * 3;
    const float px = bp[0], py = bp[1], pz = bp[2];   // uniform -> broadcast

    // base cell of the ball's low corner; {i,i+1} covers [p-3, p+3] per dim
    int ix = (int)floorf((px - 3.0f + GLO) * (1.0f / CS));
    int iy = (int)floorf((py - 3.0f + GLO) * (1.0f / CS));
    int iz = (int)floorf((pz - 3.0f + GLO) * (1.0f / CS));
    ix = min(max(ix, 0), NG - 2);
    iy = min(max(iy, 0), NG - 2);
    iz = min(max(iz, 0), NG - 2);

    float r = 0.0f;
#pragma unroll
    for (int s = 0; s < 8; ++s) {
        const int cell = ((iz + (s >> 2)) * NG + (iy + ((s >> 1) & 1))) * NG
                       + (ix + (s & 1));
        const int c = min(cnt[cell], CAP);              // wave-uniform
        const float4* bk = bucket + (size_t)cell * CAP;
        for (int j = lane; j < c; j += 64) {            // coalesced float4
            const float4 t = bk[j];
            const float dx = px - t.x, dy = py - t.y, dz = pz - t.z;
            const float d2 = fmaf(dx, dx, fmaf(dy, dy, dz * dz));
            if (d2 < 9.0f) {
                const float cc = 3.0f - __builtin_amdgcn_sqrtf(d2);
                r = fmaf(cc, cc, r);
            }
        }
    }

#pragma unroll
    for (int off = 32; off > 0; off >>= 1) r += __shfl_down(r, off);
    if (lane == 0) repel_pt[pi] = r;
}

// ---- final reduce: fold chunk mins, exact k-smallest, + repel fold ----
__global__ __launch_bounds__(256) void binder_reduce_kernel(
    const float* __restrict__ min_part,    // [B, MC, N]
    const float* __restrict__ repel_pt,    // [B * N]
    float* __restrict__ out)               // [B]
{
    __shared__ unsigned us[NN];
    __shared__ float wsum[4];
    __shared__ int   wcnt[4];
    __shared__ float wrep[4];

    const int b    = blockIdx.x;
    const int tid  = threadIdx.x;
    const int lane = tid & 63;
    const int wid  = tid >> 6;

    const float4* mp = (const float4*)min_part + (size_t)b * MC * (NN / 4) + tid;
    float4 a = mp[0];
    for (int c = 1; c < MC; ++c) {
        const float4 q = mp[(size_t)c * (NN / 4)];
        a.x = fminf(a.x, q.x); a.y = fminf(a.y, q.y);
        a.z = fminf(a.z, q.z); a.w = fminf(a.w, q.w);
    }
    unsigned u[4] = {__float_as_uint(a.x), __float_as_uint(a.y),
                     __float_as_uint(a.z), __float_as_uint(a.w)};
    us[tid * 4 + 0] = u[0];
    us[tid * 4 + 1] = u[1];
    us[tid * 4 + 2] = u[2];
    us[tid * 4 + 3] = u[3];
    __syncthreads();

    unsigned ub[16];
#pragma unroll
    for (int i = 0; i < 16; ++i) ub[i] = us[lane + 64 * i];

    // bisection: invariant count(x < lo) < KSEL; final lo = KSEL-th smallest.
    unsigned lo = 0u;
    for (int bit = 30; bit >= 0; --bit) {
        const unsigned mid = lo | (1u << bit);
        int c = 0;
#pragma unroll
        for (int i = 0; i < 16; ++i) c += (ub[i] < mid) ? 1 : 0;
#pragma unroll
        for (int off = 32; off > 0; off >>= 1) c += __shfl_down(c, off);
        c = __shfl(c, 0);
        if (c < KSEL) lo = mid;
    }

    float sum = 0.0f;
    int   cl  = 0;
#pragma unroll
    for (int i = 0; i < 4; ++i) {
        if (u[i] < lo) {
            sum += __builtin_amdgcn_sqrtf(__uint_as_float(u[i]));
            ++cl;
        }
    }
#pragma unroll
    for (int off = 32; off > 0; off >>= 1) {
        sum += __shfl_down(sum, off);
        cl  += __shfl_down(cl, off);
    }
    if (lane == 0) { wsum[wid] = sum; wcnt[wid] = cl; }

    // repel per-point fold: 1024 floats, coalesced float4
    const float4 rp = ((const float4*)repel_pt)[b * (NN / 4) + tid];
    float r = (rp.x + rp.y) + (rp.z + rp.w);
#pragma unroll
    for (int off = 32; off > 0; off >>= 1) r += __shfl_down(r, off);
    if (lane == 0) wrep[wid] = r;
    __syncthreads();

    if (tid == 0) {
        const float total = wsum[0] + wsum[1] + wsum[2] + wsum[3];
        const int   cnt2  = wcnt[0] + wcnt[1] + wcnt[2] + wcnt[3];
        const float att   = total + (float)(KSEL - cnt2)
                                    * __builtin_amdgcn_sqrtf(__uint_as_float(lo));
        const float rsum  = wrep[0] + wrep[1] + wrep[2] + wrep[3];
        out[b] = 10.0f * (att / (float)KSEL) + 5.0f * rsum;
    }
}

extern "C" void kernel_launch(void* const* d_in, const int* in_sizes, int n_in,
                              void* d_out, int out_size, void* d_ws, size_t ws_size,
                              hipStream_t stream) {
    const float* binder = (const float*)d_in[0];   // [16,1024,3] fp32
    const float* target = (const float*)d_in[1];   // [8192,3]   fp32
    float* out = (float*)d_out;                    // [16]       fp32

    // ws layout: min_part 8 MiB | repel_pt 64 KiB | cnt 32 KiB | buckets 32 MiB
    char* w = (char*)d_ws;
    float*  min_part = (float*)w;
    float*  repel_pt = (float*)(w + (8u << 20));
    int*    cnt      = (int*)(w + (8u << 20) + (64u << 10));
    float4* bucket   = (float4*)(w + (8u << 20) + (64u << 10) + (32u << 10));

    hipMemsetAsync(cnt, 0, NCELL * sizeof(int), stream);

    binder_bin_kernel<<<MM / 256, 256, 0, stream>>>(target, cnt, bucket);
    dim3 g1(MC, BB / 2);   // 128 x 8 = 1024 blocks
    binder_min_kernel<<<g1, 256, 0, stream>>>(binder, target, min_part);
    binder_repel_kernel<<<(BB * NN) / 4, 256, 0, stream>>>(binder, cnt, bucket, repel_pt);
    binder_reduce_kernel<<<BB, 256, 0, stream>>>(min_part, repel_pt, out);
}